// Round 1
// baseline (2794.703 us; speedup 1.0000x reference)
//
#include <hip/hip_runtime.h>
#include <math.h>

// Problem constants (match reference)
#define BATCH    8
#define NFFT     1024
#define HOPSZ    256
#define NBINS    513        // NFFT/2 + 1
#define SROW     516        // padded row stride (elements) for spec/mag/rebprev rows
#define TFRAMES  1024       // frames per batch in the GL loop (== T)
#define NBLK     (BATCH * TFRAMES)     // 8192 rows
#define LOUT     261888     // HOP*(T-1) : audio length per batch
#define YLEN     262912     // NFFT + HOP*(TFRAMES-1) : full overlap-add length
#define NITER    32

// LDS skew: physical = i + i/32 → breaks power-of-2 stride bank conflicts
#define LDSIDX(i) ((i) + ((i) >> 5))
#define LDSBUF    1056      // 1024 + 32

// ---------------------------------------------------------------------------
// Radix-4 Stockham 1024-pt complex FFT in LDS. SIGN=-1 forward, +1 inverse
// (inverse is unscaled; 1/N folded into the window table by the caller).
// Input in (reA,imA); result lands in (reB,imB) after 5 stages.
// Derivation: stage t: s=4^t, m=256/s; reads are always at tid+256*r since
// q + s*p == tid; writes at (4*tid - 3*q) + s*j. Verified vs N=16 by hand.
// ---------------------------------------------------------------------------
template <int SIGN>
__device__ __forceinline__ void fft1024(float* reA, float* imA, float* reB, float* imB,
                                        const float2* __restrict__ tw, int tid)
{
    float *sr = reA, *si = imA, *dr = reB, *di = imB;
    const int i0 = LDSIDX(tid);
    const int i1 = LDSIDX(tid + 256);
    const int i2 = LDSIDX(tid + 512);
    const int i3 = LDSIDX(tid + 768);
#pragma unroll
    for (int st = 0; st < 5; ++st) {
        const int s = 1 << (2 * st);
        const int q = tid & (s - 1);
        const int p = tid >> (2 * st);

        float a0r = sr[i0], a0i = si[i0];
        float a1r = sr[i1], a1i = si[i1];
        float a2r = sr[i2], a2i = si[i2];
        float a3r = sr[i3], a3i = si[i3];

        float Ar = a0r + a2r, Ai = a0i + a2i;
        float Br = a0r - a2r, Bi = a0i - a2i;
        float Cr = a1r + a3r, Ci = a1i + a3i;
        float Dr = a1r - a3r, Di = a1i - a3i;

        float y0r = Ar + Cr, y0i = Ai + Ci;
        float y2r = Ar - Cr, y2i = Ai - Ci;
        float y1r, y1i, y3r, y3i;
        if (SIGN < 0) {              // forward: y1 = B - i*D ; y3 = B + i*D
            y1r = Br + Di; y1i = Bi - Dr;
            y3r = Br - Di; y3i = Bi + Dr;
        } else {                     // inverse: y1 = B + i*D ; y3 = B - i*D
            y1r = Br - Di; y1i = Bi + Dr;
            y3r = Br + Di; y3i = Bi - Dr;
        }

        const int x = p * s;         // twiddle index: w_j = exp(-2*pi*i * j*x / 1024)
        float2 w1 = tw[x], w2 = tw[2 * x], w3 = tw[3 * x];
        if (SIGN > 0) { w1.y = -w1.y; w2.y = -w2.y; w3.y = -w3.y; }

        const int ob = 4 * tid - 3 * q;
        const int o0 = LDSIDX(ob);
        const int o1 = LDSIDX(ob + s);
        const int o2 = LDSIDX(ob + 2 * s);
        const int o3 = LDSIDX(ob + 3 * s);
        dr[o0] = y0r;                         di[o0] = y0i;
        dr[o1] = y1r * w1.x - y1i * w1.y;     di[o1] = y1r * w1.y + y1i * w1.x;
        dr[o2] = y2r * w2.x - y2i * w2.y;     di[o2] = y2r * w2.y + y2i * w2.x;
        dr[o3] = y3r * w3.x - y3i * w3.y;     di[o3] = y3r * w3.y + y3i * w3.x;
        __syncthreads();
        float* tp;
        tp = sr; sr = dr; dr = tp;
        tp = si; si = di; di = tp;
    }
}

// ---------------------------------------------------------------------------
// Tables: twiddles (double-precision trig, rounded to fp32), hann window,
// window/1024 (folds irfft's 1/N into the synthesis window).
// ---------------------------------------------------------------------------
__global__ void k_tables(float2* tw, float* win, float* wscl)
{
    int i = blockIdx.x * blockDim.x + threadIdx.x;
    if (i < 1024) {
        double th = -2.0 * M_PI * (double)i / 1024.0;
        tw[i] = make_float2((float)cos(th), (float)sin(th));
        double w = 0.5 - 0.5 * cos(2.0 * M_PI * (double)i / 1024.0);
        win[i]  = (float)w;
        wscl[i] = (float)(w / 1024.0);
    }
}

// wsq_inv[t] = 1 / max(sum_f win[t-256f]^2, 1e-8)  over valid frames (fp32 like ref)
__global__ void k_wsq(const float* __restrict__ win, float* __restrict__ wsqinv)
{
    int t = blockIdx.x * blockDim.x + threadIdx.x;
    if (t >= YLEN) return;
    int fhi = t >> 8;
    int flo = fhi - 3; if (flo < 0) flo = 0;
    if (fhi > TFRAMES - 1) fhi = TFRAMES - 1;
    float acc = 0.f;
    for (int f = flo; f <= fhi; ++f) {
        float w = win[t - (f << 8)];
        acc += w * w;
    }
    float m = acc > 1e-8f ? acc : 1e-8f;
    wsqinv[t] = 1.0f / m;
}

// ---------------------------------------------------------------------------
// Init: mag[b,t,k] = |sum_m melinv[k,m]*exp(mel[b,m,t])| ;
//       spec[b,t,k] = mag * exp(2*pi*i*angles0[b,k,t])   (frame-major layout)
// ---------------------------------------------------------------------------
__global__ __launch_bounds__(256) void k_specinit(const float* __restrict__ mel,
                                                  const float* __restrict__ melinv,
                                                  const float* __restrict__ ang0,
                                                  float* __restrict__ mag,
                                                  float2* __restrict__ spec)
{
    int blk = blockIdx.x;
    int b = blk >> 10;
    int t = blk & 1023;
    int tid = threadIdx.x;
    __shared__ float em[80];
    if (tid < 80) em[tid] = expf(mel[((size_t)b * 80 + tid) * 1024 + t]);
    __syncthreads();
    size_t row = (size_t)blk * SROW;
    for (int k = tid; k < NBINS; k += 256) {
        const float* mrow = melinv + k * 80;
        float s = 0.f;
        for (int m = 0; m < 80; ++m) s += mrow[m] * em[m];
        float mg = fabsf(s);
        float a = ang0[((size_t)b * NBINS + k) * 1024 + t];
        float sn, cn;
        sincospif(2.0f * a, &sn, &cn);
        mag[row + k] = mg;
        spec[row + k] = make_float2(mg * cn, mg * sn);
    }
}

// ---------------------------------------------------------------------------
// ISTFT half: frames[b,f,n] = Re(ifft1024(hermitian(spec[b,f,:])))[n] * win[n]/1024
// ---------------------------------------------------------------------------
__global__ __launch_bounds__(256) void k_ifft(const float2* __restrict__ spec,
                                              const float2* __restrict__ tw,
                                              const float* __restrict__ wscl,
                                              float* __restrict__ frames)
{
    __shared__ float reA[LDSBUF], imA[LDSBUF], reB[LDSBUF], imB[LDSBUF];
    int blk = blockIdx.x;
    int tid = threadIdx.x;
    size_t row = (size_t)blk * SROW;
    for (int k = tid; k < NBINS; k += 256) {
        float2 v = spec[row + k];
        reA[LDSIDX(k)] = v.x;
        imA[LDSIDX(k)] = v.y;
        if (k > 0 && k < 512) {
            int kk = 1024 - k;
            reA[LDSIDX(kk)] = v.x;
            imA[LDSIDX(kk)] = -v.y;
        }
    }
    __syncthreads();
    fft1024<1>(reA, imA, reB, imB, tw, tid);
    size_t frow = (size_t)blk * 1024;
#pragma unroll
    for (int r = 0; r < 4; ++r) {
        int n = tid + 256 * r;
        frames[frow + n] = reB[LDSIDX(n)] * wscl[n];
    }
}

// ---------------------------------------------------------------------------
// STFT half + phase update:
//  - gather overlap-add (<=4 frames) with 1/wsq, reflect-pad, analysis window
//  - forward FFT
//  - v = reb - beta*reb_prev ; spec = mag * v/(|v|+1e-16) ; reb_prev = reb
// ---------------------------------------------------------------------------
__global__ __launch_bounds__(256) void k_fft(const float* __restrict__ frames,
                                             const float* __restrict__ mag,
                                             const float2* __restrict__ tw,
                                             const float* __restrict__ win,
                                             const float* __restrict__ wsqinv,
                                             float2* __restrict__ spec,
                                             float2* __restrict__ rebprev,
                                             float beta)
{
    __shared__ float reA[LDSBUF], imA[LDSBUF], reB[LDSBUF], imB[LDSBUF];
    int blk = blockIdx.x;
    int tid = threadIdx.x;
    int b = blk >> 10;
    int f = blk & 1023;
    const float* fb = frames + (size_t)b * (TFRAMES * 1024);
#pragma unroll
    for (int r = 0; r < 4; ++r) {
        int n = tid + 256 * r;
        int j = f * HOPSZ + n - 512;              // position in inv (pre reflect)
        if (j < 0) j = -j;                        // reflect left
        else if (j >= LOUT) j = 2 * LOUT - 2 - j; // reflect right
        int t = j + 512;                          // position in full overlap-add signal
        int fhi = t >> 8;
        int flo = fhi - 3; if (flo < 0) flo = 0;
        if (fhi > TFRAMES - 1) fhi = TFRAMES - 1;
        float acc = 0.f;
        for (int ff = flo; ff <= fhi; ++ff)
            acc += fb[(size_t)ff * 1024 + (t - (ff << 8))];
        float x = acc * wsqinv[t] * win[n];
        reA[LDSIDX(n)] = x;
        imA[LDSIDX(n)] = 0.f;
    }
    __syncthreads();
    fft1024<-1>(reA, imA, reB, imB, tw, tid);
    size_t row = (size_t)blk * SROW;
    for (int k = tid; k < NBINS; k += 256) {
        float rr = reB[LDSIDX(k)];
        float ri = imB[LDSIDX(k)];
        float2 pv = rebprev[row + k];
        float vx = rr - beta * pv.x;
        float vy = ri - beta * pv.y;
        float a = sqrtf(vx * vx + vy * vy) + 1e-16f;
        float sc = mag[row + k] / a;
        spec[row + k] = make_float2(vx * sc, vy * sc);
        rebprev[row + k] = make_float2(rr, ri);
    }
}

// Final overlap-add -> audio out (crop 512 each side)
__global__ __launch_bounds__(256) void k_gather(const float* __restrict__ frames,
                                                const float* __restrict__ wsqinv,
                                                float* __restrict__ out)
{
    int idx = blockIdx.x * 256 + threadIdx.x;
    if (idx >= BATCH * LOUT) return;
    int b = idx / LOUT;
    int j = idx - b * LOUT;
    int t = j + 512;
    const float* fb = frames + (size_t)b * (TFRAMES * 1024);
    int fhi = t >> 8;
    int flo = fhi - 3; if (flo < 0) flo = 0;
    if (fhi > TFRAMES - 1) fhi = TFRAMES - 1;
    float acc = 0.f;
    for (int ff = flo; ff <= fhi; ++ff)
        acc += fb[(size_t)ff * 1024 + (t - (ff << 8))];
    out[idx] = acc * wsqinv[t];
}

// ---------------------------------------------------------------------------
extern "C" void kernel_launch(void* const* d_in, const int* in_sizes, int n_in,
                              void* d_out, int out_size, void* d_ws, size_t ws_size,
                              hipStream_t stream)
{
    const float* mel    = (const float*)d_in[0];   // [8, 80, 1024]
    const float* melinv = (const float*)d_in[1];   // [513, 80]
    const float* ang0   = (const float*)d_in[2];   // [8, 513, 1024]
    float* out = (float*)d_out;                    // [8, 261888]

    char* ws = (char*)d_ws;
    size_t off = 0;
    auto carve = [&](size_t bytes) -> void* {
        void* p = ws + off;
        off += (bytes + 255) & ~(size_t)255;
        return p;
    };
    float2* tw     = (float2*)carve(1024 * sizeof(float2));
    float*  win    = (float*) carve(1024 * sizeof(float));
    float*  wscl   = (float*) carve(1024 * sizeof(float));
    float*  wsqinv = (float*) carve((size_t)YLEN * sizeof(float));
    float*  mag    = (float*) carve((size_t)NBLK * SROW * sizeof(float));
    float2* spec   = (float2*)carve((size_t)NBLK * SROW * sizeof(float2));
    float2* rebp   = (float2*)carve((size_t)NBLK * SROW * sizeof(float2));
    float*  frames = (float*) carve((size_t)NBLK * 1024 * sizeof(float));
    (void)ws_size; (void)in_sizes; (void)n_in; (void)out_size;

    const float beta = (float)(0.99 / 1.99);

    hipLaunchKernelGGL(k_tables, dim3(4), dim3(256), 0, stream, tw, win, wscl);
    hipLaunchKernelGGL(k_wsq, dim3((YLEN + 255) / 256), dim3(256), 0, stream, win, wsqinv);
    hipLaunchKernelGGL(k_specinit, dim3(NBLK), dim3(256), 0, stream, mel, melinv, ang0, mag, spec);
    (void)hipMemsetAsync(rebp, 0, (size_t)NBLK * SROW * sizeof(float2), stream);

    for (int it = 0; it < NITER; ++it) {
        hipLaunchKernelGGL(k_ifft, dim3(NBLK), dim3(256), 0, stream, spec, tw, wscl, frames);
        hipLaunchKernelGGL(k_fft, dim3(NBLK), dim3(256), 0, stream,
                           frames, mag, tw, win, wsqinv, spec, rebp, beta);
    }
    hipLaunchKernelGGL(k_ifft, dim3(NBLK), dim3(256), 0, stream, spec, tw, wscl, frames);
    hipLaunchKernelGGL(k_gather, dim3((BATCH * LOUT + 255) / 256), dim3(256), 0, stream,
                       frames, wsqinv, out);
}

// Round 2
// 2298.954 us; speedup vs baseline: 1.2156x; 1.2156x over previous
//
#include <hip/hip_runtime.h>
#include <math.h>

// Problem constants (match reference)
#define BATCH    8
#define NFFT     1024
#define HOPSZ    256
#define NBINS    513        // NFFT/2 + 1
#define SROW     516        // padded row stride (elements) for spec/mag/rebprev rows
#define TFRAMES  1024       // frames per batch (== T)
#define NBLK     (BATCH * TFRAMES)     // 8192 rows
#define LOUT     261888     // HOP*(T-1) : audio length per batch
#define YLEN     262912     // NFFT + HOP*(TFRAMES-1)
#define NITER    32

// LDS skew: physical = i + i/32 → breaks power-of-2 stride bank conflicts
#define LDSIDX(i) ((i) + ((i) >> 5))
#define LDSBUF    532       // LDSIDX(512)=528 → 529 needed

// ---------------------------------------------------------------------------
// 8-point DFT in registers. SIGN=-1 forward, +1 inverse (unscaled).
// Built as two radix-4 DFTs (even/odd) + W8 combine. Outputs are TRUE DFT
// order (no bit reversal). Verified: dft8(delta_1) = W8^j.
// ---------------------------------------------------------------------------
template <int SIGN>
__device__ __forceinline__ void dft8(const float xr[8], const float xi[8],
                                     float yr[8], float yi[8])
{
    const float r2 = 0.70710678118654752f;
    // E = DFT4(x0,x2,x4,x6)
    float Ar = xr[0] + xr[4], Ai = xi[0] + xi[4];
    float Br = xr[0] - xr[4], Bi = xi[0] - xi[4];
    float Cr = xr[2] + xr[6], Ci = xi[2] + xi[6];
    float Dr = xr[2] - xr[6], Di = xi[2] - xi[6];
    float E0r = Ar + Cr, E0i = Ai + Ci;
    float E2r = Ar - Cr, E2i = Ai - Ci;
    float E1r, E1i, E3r, E3i;
    if (SIGN < 0) { E1r = Br + Di; E1i = Bi - Dr; E3r = Br - Di; E3i = Bi + Dr; }
    else          { E1r = Br - Di; E1i = Bi + Dr; E3r = Br + Di; E3i = Bi - Dr; }
    // O = DFT4(x1,x3,x5,x7)
    float ar = xr[1] + xr[5], ai = xi[1] + xi[5];
    float br = xr[1] - xr[5], bi = xi[1] - xi[5];
    float cr = xr[3] + xr[7], ci = xi[3] + xi[7];
    float dr = xr[3] - xr[7], di = xi[3] - xi[7];
    float O0r = ar + cr, O0i = ai + ci;
    float O2r = ar - cr, O2i = ai - ci;
    float O1r, O1i, O3r, O3i;
    if (SIGN < 0) { O1r = br + di; O1i = bi - dr; O3r = br - di; O3i = bi + dr; }
    else          { O1r = br - di; O1i = bi + dr; O3r = br + di; O3i = bi - dr; }
    // t_j = W8^{±j} * O_j
    float t1r, t1i, t2r, t2i, t3r, t3i;
    if (SIGN < 0) {
        t1r = r2 * (O1r + O1i); t1i = r2 * (O1i - O1r);   // (r,-r)*z
        t2r = O2i;              t2i = -O2r;               // -i*z
        t3r = r2 * (O3i - O3r); t3i = -r2 * (O3r + O3i);  // (-r,-r)*z
    } else {
        t1r = r2 * (O1r - O1i); t1i = r2 * (O1i + O1r);   // (r,r)*z
        t2r = -O2i;             t2i = O2r;                // +i*z
        t3r = -r2 * (O3r + O3i); t3i = r2 * (O3r - O3i);  // (-r,r)*z
    }
    yr[0] = E0r + O0r; yi[0] = E0i + O0i;  yr[4] = E0r - O0r; yi[4] = E0i - O0i;
    yr[1] = E1r + t1r; yi[1] = E1i + t1i;  yr[5] = E1r - t1r; yi[5] = E1i - t1i;
    yr[2] = E2r + t2r; yi[2] = E2i + t2i;  yr[6] = E2r - t2r; yi[6] = E2i - t2i;
    yr[3] = E3r + t3r; yi[3] = E3i + t3i;  yr[7] = E3r - t3r; yi[7] = E3i - t3i;
}

// Stockham radix-8 stage write: y_j twiddled by w512^{j*p*S}, written at
// q + 8*S*p + S*j.  (S=64 → p=0 → all twiddles = tw[0] = 1, harmless.)
template <int SIGN, int S>
__device__ __forceinline__ void stage_write(float* lre, float* lim,
                                            const float yr[8], const float yi[8],
                                            int tid, const float2* __restrict__ tw)
{
    const int q = tid & (S - 1);
    const int p = tid / S;
    const int e = p * S;
    const int base = q + 8 * S * p;
#pragma unroll
    for (int j = 0; j < 8; ++j) {
        float vr = yr[j], vi = yi[j];
        if (j > 0) {
            float2 w = tw[j * e];
            float wr = w.x, wi = (SIGN < 0) ? w.y : -w.y;
            float tr = vr * wr - vi * wi;
            vi = vr * wi + vi * wr;
            vr = tr;
        }
        int o = LDSIDX(base + S * j);
        lre[o] = vr; lim[o] = vi;
    }
}

__device__ __forceinline__ void stage_read(const float* lre, const float* lim,
                                           float xr[8], float xi[8], int tid)
{
#pragma unroll
    for (int j = 0; j < 8; ++j) {
        int o = LDSIDX(tid + 64 * j);
        xr[j] = lre[o]; xi[j] = lim[o];
    }
}

// Full 512-pt FFT: stage0 inputs in xr/xi (logical positions tid+64j),
// results in yr/yi (logical positions tid+64j). 3 radix-8 stages, in-place LDS.
template <int SIGN>
__device__ __forceinline__ void fft512(float* lre, float* lim,
                                       float xr[8], float xi[8],
                                       float yr[8], float yi[8],
                                       int tid, const float2* __restrict__ tw)
{
    dft8<SIGN>(xr, xi, yr, yi);
    stage_write<SIGN, 1>(lre, lim, yr, yi, tid, tw);
    __syncthreads();
    stage_read(lre, lim, xr, xi, tid);
    __syncthreads();                       // in-place: all reads before any write
    dft8<SIGN>(xr, xi, yr, yi);
    stage_write<SIGN, 8>(lre, lim, yr, yi, tid, tw);
    __syncthreads();
    stage_read(lre, lim, xr, xi, tid);
    dft8<SIGN>(xr, xi, yr, yi);            // stage2: p=0 → no twiddles, stays in regs
}

// ---------------------------------------------------------------------------
// Tables: tw512[x]=e^{-2pi i x/512}, twh[k]=e^{-2pi i k/1024}, hann window,
// win/512 (folds the packed-irfft 1/(N/2) into the synthesis window).
// ---------------------------------------------------------------------------
__global__ void k_tables(float2* tw512, float2* twh, float* win, float* wscl)
{
    int i = blockIdx.x * blockDim.x + threadIdx.x;
    if (i < 512) {
        double t1 = -2.0 * M_PI * (double)i / 512.0;
        tw512[i] = make_float2((float)cos(t1), (float)sin(t1));
        double t2 = -2.0 * M_PI * (double)i / 1024.0;
        twh[i] = make_float2((float)cos(t2), (float)sin(t2));
    }
    if (i < 1024) {
        double w = 0.5 - 0.5 * cos(2.0 * M_PI * (double)i / 1024.0);
        win[i]  = (float)w;
        wscl[i] = (float)(w / 512.0);
    }
}

// wsq_inv[t] = 1 / max(sum_f win[t-256f]^2, 1e-8)
__global__ void k_wsq(const float* __restrict__ win, float* __restrict__ wsqinv)
{
    int t = blockIdx.x * blockDim.x + threadIdx.x;
    if (t >= YLEN) return;
    int fhi = t >> 8;
    int flo = fhi - 3; if (flo < 0) flo = 0;
    if (fhi > TFRAMES - 1) fhi = TFRAMES - 1;
    float acc = 0.f;
    for (int f = flo; f <= fhi; ++f) {
        float w = win[t - (f << 8)];
        acc += w * w;
    }
    float m = acc > 1e-8f ? acc : 1e-8f;
    wsqinv[t] = 1.0f / m;
}

// melinvT[m*513+k] = melinv[k*80+m]
__global__ void k_melinvT(const float* __restrict__ melinv, float* __restrict__ melinvT)
{
    int idx = blockIdx.x * blockDim.x + threadIdx.x;
    if (idx >= 80 * NBINS) return;
    int m = idx / NBINS, k = idx - m * NBINS;
    melinvT[idx] = melinv[k * 80 + m];
}

// angT[b][t][k] = ang0[b][k][t] — LDS tiled transpose
__global__ __launch_bounds__(256) void k_angT(const float* __restrict__ ang0,
                                              float* __restrict__ angT)
{
    __shared__ float tile[32][33];
    int kt = blockIdx.x * 32, tt = blockIdx.y * 32, b = blockIdx.z;
    int tx = threadIdx.x & 31, ty = threadIdx.x >> 5;   // 32x8
#pragma unroll
    for (int i = 0; i < 32; i += 8) {
        int k = kt + ty + i, t = tt + tx;
        if (k < NBINS) tile[ty + i][tx] = ang0[((size_t)b * NBINS + k) * 1024 + t];
    }
    __syncthreads();
#pragma unroll
    for (int i = 0; i < 32; i += 8) {
        int t = tt + ty + i, k = kt + tx;
        if (k < NBINS) angT[((size_t)b * 1024 + t) * NBINS + k] = tile[tx][ty + i];
    }
}

// ---------------------------------------------------------------------------
// Init: mag[b,t,k] = |sum_m melinvT[m,k]*exp(mel[b,m,t])| ;
//       spec[b,t,k] = mag * exp(2*pi*i*angT[b,t,k])
// ---------------------------------------------------------------------------
__global__ __launch_bounds__(256) void k_specinit(const float* __restrict__ mel,
                                                  const float* __restrict__ melinvT,
                                                  const float* __restrict__ angT,
                                                  float* __restrict__ mag,
                                                  float2* __restrict__ spec)
{
    int blk = blockIdx.x;
    int b = blk >> 10;
    int t = blk & 1023;
    int tid = threadIdx.x;
    __shared__ float em[80];
    if (tid < 80) em[tid] = expf(mel[((size_t)b * 80 + tid) * 1024 + t]);
    __syncthreads();
    size_t row = (size_t)blk * SROW;
    size_t arow = ((size_t)b * 1024 + t) * NBINS;
    for (int k = tid; k < NBINS; k += 256) {
        float s = 0.f;
#pragma unroll 8
        for (int m = 0; m < 80; ++m) s += melinvT[m * NBINS + k] * em[m];
        float mg = fabsf(s);
        float a = angT[arow + k];
        float sn, cn;
        sincospif(2.0f * a, &sn, &cn);
        mag[row + k] = mg;
        spec[row + k] = make_float2(mg * cn, mg * sn);
    }
}

// ---------------------------------------------------------------------------
// ISTFT half via packed real-IFFT: X[0..512] (imag of DC/Nyquist dropped, as
// irfft does) → Z[k]=Xe+i*Xo → ifft512 → x[2n]=Re z, x[2n+1]=Im z; window+1/512.
// One wave per row.
// ---------------------------------------------------------------------------
__global__ __launch_bounds__(64) void k_ifft(const float2* __restrict__ spec,
                                             const float2* __restrict__ tw512,
                                             const float2* __restrict__ twh,
                                             const float* __restrict__ wscl,
                                             float* __restrict__ frames)
{
    __shared__ float lre[LDSBUF], lim[LDSBUF];
    int blk = blockIdx.x;
    int tid = threadIdx.x;
    size_t row = (size_t)blk * SROW;
#pragma unroll
    for (int r = 0; r < 8; ++r) {
        int k = tid + 64 * r;
        float2 v = spec[row + k];
        if (k == 0) v.y = 0.f;
        int o = LDSIDX(k);
        lre[o] = v.x; lim[o] = v.y;
    }
    if (tid == 0) {
        float2 v = spec[row + 512];
        lre[LDSIDX(512)] = v.x; lim[LDSIDX(512)] = 0.f;
    }
    __syncthreads();
    float xr[8], xi[8], yr[8], yi[8];
#pragma unroll
    for (int r = 0; r < 8; ++r) {            // pre-twist: Z[k] = Xe[k] + i*Xo[k]
        int k = tid + 64 * r, m = 512 - k;
        int ok = LDSIDX(k), om = LDSIDX(m);
        float Xkr = lre[ok], Xki = lim[ok];
        float Xmr = lre[om], Xmi = lim[om];
        float Ar = 0.5f * (Xkr + Xmr), Ai = 0.5f * (Xki - Xmi);   // (Xk+conj(Xm))/2
        float Sr = 0.5f * (Xkr - Xmr), Si = 0.5f * (Xki + Xmi);   // (Xk-conj(Xm))/2
        float2 W = twh[k];
        float Xor = W.x * Sr + W.y * Si;     // conj(W)*S
        float Xoi = W.x * Si - W.y * Sr;
        xr[r] = Ar - Xoi;                    // A + i*Xo
        xi[r] = Ai + Xor;
    }
    __syncthreads();                          // all twist reads before FFT writes
    fft512<1>(lre, lim, xr, xi, yr, yi, tid, tw512);
    size_t frow = (size_t)blk * 1024;
#pragma unroll
    for (int j = 0; j < 8; ++j) {
        int m = tid + 64 * j;
        float2 ws = *(const float2*)&wscl[2 * m];
        float2 o;
        o.x = yr[j] * ws.x;
        o.y = yi[j] * ws.y;
        *(float2*)&frames[frow + 2 * m] = o;
    }
}

// overlap-add gather for one sample (reflect-pad, 1/wsq)
__device__ __forceinline__ float oa_sample(const float* __restrict__ fb, int f, int n,
                                           const float* __restrict__ wsqinv)
{
    int j = f * HOPSZ + n - 512;
    if (j < 0) j = -j;
    else if (j >= LOUT) j = 2 * LOUT - 2 - j;
    int t = j + 512;
    int fhi = t >> 8;
    int flo = fhi - 3; if (flo < 0) flo = 0;
    if (fhi > TFRAMES - 1) fhi = TFRAMES - 1;
    float acc = 0.f;
    for (int ff = flo; ff <= fhi; ++ff)
        acc += fb[(size_t)ff * 1024 + (t - (ff << 8))];
    return acc * wsqinv[t];
}

// ---------------------------------------------------------------------------
// STFT half + phase update, packed real-FFT: gather windowed frame →
// z[m]=x[2m]+i*x[2m+1] → fft512 → post-twist to X[0..512] → GL update.
// ---------------------------------------------------------------------------
__global__ __launch_bounds__(64) void k_fft(const float* __restrict__ frames,
                                            const float* __restrict__ mag,
                                            const float2* __restrict__ tw512,
                                            const float2* __restrict__ twh,
                                            const float* __restrict__ win,
                                            const float* __restrict__ wsqinv,
                                            float2* __restrict__ spec,
                                            float2* __restrict__ rebprev,
                                            float beta)
{
    __shared__ float lre[LDSBUF], lim[LDSBUF];
    int blk = blockIdx.x;
    int tid = threadIdx.x;
    int b = blk >> 10;
    int f = blk & 1023;
    const float* fb = frames + (size_t)b * (TFRAMES * 1024);
    float xr[8], xi[8], yr[8], yi[8];
#pragma unroll
    for (int r = 0; r < 8; ++r) {
        int m = tid + 64 * r;
        float s0 = oa_sample(fb, f, 2 * m, wsqinv);
        float s1 = oa_sample(fb, f, 2 * m + 1, wsqinv);
        float2 w2 = *(const float2*)&win[2 * m];
        xr[r] = s0 * w2.x;
        xi[r] = s1 * w2.y;
    }
    fft512<-1>(lre, lim, xr, xi, yr, yi, tid, tw512);
    // Z to LDS for cross-lane twist (stage2 read/write sets are lane-private)
#pragma unroll
    for (int j = 0; j < 8; ++j) {
        int o = LDSIDX(tid + 64 * j);
        lre[o] = yr[j]; lim[o] = yi[j];
    }
    __syncthreads();
    size_t row = (size_t)blk * SROW;
#pragma unroll
    for (int r = 0; r < 9; ++r) {
        int k = (r < 8) ? (tid + 64 * r) : 512;
        if (r == 8 && tid != 0) break;
        int kk = k & 511, m = (512 - k) & 511;
        float Zkr = lre[LDSIDX(kk)], Zki = lim[LDSIDX(kk)];
        float Zmr = lre[LDSIDX(m)],  Zmi = lim[LDSIDX(m)];
        float Ar = 0.5f * (Zkr + Zmr), Ai = 0.5f * (Zki - Zmi);
        float Sr = 0.5f * (Zkr - Zmr), Si = 0.5f * (Zki + Zmi);
        float wr, wi;
        if (k == 512) { wr = -1.f; wi = 0.f; }
        else { float2 W = twh[k]; wr = W.x; wi = W.y; }
        float Ur = wr * Sr - wi * Si;
        float Ui = wr * Si + wi * Sr;
        float Xr = Ar + Ui;                   // A - i*(W*S)
        float Xi = Ai - Ur;
        float2 pv = rebprev[row + k];
        float vx = Xr - beta * pv.x;
        float vy = Xi - beta * pv.y;
        float a = sqrtf(vx * vx + vy * vy) + 1e-16f;
        float sc = mag[row + k] / a;
        spec[row + k] = make_float2(vx * sc, vy * sc);
        rebprev[row + k] = make_float2(Xr, Xi);
    }
}

// Final overlap-add -> audio out (crop 512 each side)
__global__ __launch_bounds__(256) void k_gather(const float* __restrict__ frames,
                                                const float* __restrict__ wsqinv,
                                                float* __restrict__ out)
{
    int idx = blockIdx.x * 256 + threadIdx.x;
    if (idx >= BATCH * LOUT) return;
    int b = idx / LOUT;
    int j = idx - b * LOUT;
    int t = j + 512;
    const float* fb = frames + (size_t)b * (TFRAMES * 1024);
    int fhi = t >> 8;
    int flo = fhi - 3; if (flo < 0) flo = 0;
    if (fhi > TFRAMES - 1) fhi = TFRAMES - 1;
    float acc = 0.f;
    for (int ff = flo; ff <= fhi; ++ff)
        acc += fb[(size_t)ff * 1024 + (t - (ff << 8))];
    out[idx] = acc * wsqinv[t];
}

// ---------------------------------------------------------------------------
extern "C" void kernel_launch(void* const* d_in, const int* in_sizes, int n_in,
                              void* d_out, int out_size, void* d_ws, size_t ws_size,
                              hipStream_t stream)
{
    const float* mel    = (const float*)d_in[0];   // [8, 80, 1024]
    const float* melinv = (const float*)d_in[1];   // [513, 80]
    const float* ang0   = (const float*)d_in[2];   // [8, 513, 1024]
    float* out = (float*)d_out;                    // [8, 261888]

    char* ws = (char*)d_ws;
    size_t off = 0;
    auto carve = [&](size_t bytes) -> void* {
        void* p = ws + off;
        off += (bytes + 255) & ~(size_t)255;
        return p;
    };
    float2* tw512   = (float2*)carve(512 * sizeof(float2));
    float2* twh     = (float2*)carve(512 * sizeof(float2));
    float*  win     = (float*) carve(1024 * sizeof(float));
    float*  wscl    = (float*) carve(1024 * sizeof(float));
    float*  wsqinv  = (float*) carve((size_t)YLEN * sizeof(float));
    float*  melinvT = (float*) carve((size_t)80 * NBINS * sizeof(float));
    float*  mag     = (float*) carve((size_t)NBLK * SROW * sizeof(float));
    float2* spec    = (float2*)carve((size_t)NBLK * SROW * sizeof(float2));
    float2* rebp    = (float2*)carve((size_t)NBLK * SROW * sizeof(float2));
    float*  frames  = (float*) carve((size_t)NBLK * 1024 * sizeof(float));
    float*  angT    = frames;  // alias: angT consumed by k_specinit before any k_ifft
    (void)ws_size; (void)in_sizes; (void)n_in; (void)out_size;

    const float beta = (float)(0.99 / 1.99);

    hipLaunchKernelGGL(k_tables, dim3(4), dim3(256), 0, stream, tw512, twh, win, wscl);
    hipLaunchKernelGGL(k_wsq, dim3((YLEN + 255) / 256), dim3(256), 0, stream, win, wsqinv);
    hipLaunchKernelGGL(k_melinvT, dim3((80 * NBINS + 255) / 256), dim3(256), 0, stream,
                       melinv, melinvT);
    hipLaunchKernelGGL(k_angT, dim3(17, 32, BATCH), dim3(256), 0, stream, ang0, angT);
    hipLaunchKernelGGL(k_specinit, dim3(NBLK), dim3(256), 0, stream,
                       mel, melinvT, angT, mag, spec);
    (void)hipMemsetAsync(rebp, 0, (size_t)NBLK * SROW * sizeof(float2), stream);

    for (int it = 0; it < NITER; ++it) {
        hipLaunchKernelGGL(k_ifft, dim3(NBLK), dim3(64), 0, stream,
                           spec, tw512, twh, wscl, frames);
        hipLaunchKernelGGL(k_fft, dim3(NBLK), dim3(64), 0, stream,
                           frames, mag, tw512, twh, win, wsqinv, spec, rebp, beta);
    }
    hipLaunchKernelGGL(k_ifft, dim3(NBLK), dim3(64), 0, stream,
                       spec, tw512, twh, wscl, frames);
    hipLaunchKernelGGL(k_gather, dim3((BATCH * LOUT + 255) / 256), dim3(256), 0, stream,
                       frames, wsqinv, out);
}